// Round 11
// baseline (224.285 us; speedup 1.0000x reference)
//
#include <hip/hip_runtime.h>
#include <hip/hip_bf16.h>
#include <stdint.h>

typedef __bf16 bf;
typedef __bf16 v8bf __attribute__((ext_vector_type(8)));
typedef float v4f __attribute__((ext_vector_type(4)));

#define SEQ   197
#define HEADS 12
#define HID   768
#define NQKV  2304
#define MTOT  12608   // 64*197
#define VP    232     // sV/sP pitch (elems): 464 B mod 128 = 80 -> 16B-slot spread

__device__ __forceinline__ void gload_lds16(const void* g, void* l) {
    __builtin_amdgcn_global_load_lds(
        (const __attribute__((address_space(1))) void*)g,
        (__attribute__((address_space(3))) void*)l, 16, 0, 0);
}

// ---------------- kernel 0: fused prep (kx + kwt + kbias in one launch) -----
__global__ void kprep(const float* __restrict__ x, bf* __restrict__ xb,
                      const float* __restrict__ wq, const float* __restrict__ wk,
                      const float* __restrict__ wv, bf* __restrict__ wt,
                      const float* __restrict__ table, float* __restrict__ bias) {
    __shared__ float t[64][65];
    const int bid = blockIdx.x;

    if (bid < 9456) {
        int idx = bid * 256 + threadIdx.x;
        float4 v = ((const float4*)x)[idx];
        bf o[4] = {(bf)v.x, (bf)v.y, (bf)v.z, (bf)v.w};
        ((uint2*)xb)[idx] = *(uint2*)o;
        return;
    }

    if (bid < 9456 + 432) {
        int bz = bid - 9456;
        int z  = bz / 144;
        int rr = bz % 144;
        int bx = rr % 12;
        int by = rr / 12;
        const float* W = (z == 0) ? wq : (z == 1 ? wk : wv);
        int kt = bx * 64, nt = by * 64;
        int r  = threadIdx.x >> 4;
        int c4 = (threadIdx.x & 15) * 4;
#pragma unroll
        for (int p = 0; p < 64; p += 16) {
            float4 v = *(const float4*)(W + (size_t)(kt + p + r) * 768 + nt + c4);
            t[p + r][c4 + 0] = v.x; t[p + r][c4 + 1] = v.y;
            t[p + r][c4 + 2] = v.z; t[p + r][c4 + 3] = v.w;
        }
        __syncthreads();
#pragma unroll
        for (int p = 0; p < 64; p += 16) {
            int i = p + r;
            bf o[4];
#pragma unroll
            for (int j = 0; j < 4; j++) o[j] = (bf)t[c4 + j][i];
            *(uint2*)(wt + (size_t)(z * 768 + nt + i) * 768 + kt + c4) = *(uint2*)o;
        }
        return;
    }

    int idx = (bid - 9888) * 256 + threadIdx.x;
    int h = idx / (208 * 208);
    int r = idx % (208 * 208);
    int i = r / 208, j = r % 208;
    float v = 0.f;
    if (i < SEQ && j < SEQ) {
        int rpi;
        if (i == 0 && j == 0)      rpi = 731;
        else if (i == 0)           rpi = 729;
        else if (j == 0)           rpi = 730;
        else {
            int hp = (i - 1) / 14, wp = (i - 1) % 14;
            int hq = (j - 1) / 14, wq = (j - 1) % 14;
            rpi = (hp - hq + 13) * 27 + (wp - wq + 13);
        }
        v = table[rpi * 12 + h];
    }
    bias[idx] = v;
}

// ---------------- kernel 3: fused QKV GEMM — round-6 family, wave tile ------
// 64x64 -> 64x128 (block 128x256, 4 waves as 2M x 2N). ONE lever: LDS
// fragment reads per MFMA 0.5 -> 0.375 and staging bytes per output 24 -> 18.
// Everything proven kept: BK=64 (128 B row pitch, the unique 0-conflict
// geometry from the BK sweep), same XOR involution, same 2-barrier loop,
// 2 blocks/CU (LDS 48 KB). Regs ~190/wave -> 2 waves/SIMD.
// C[12608][2304] = Xb[12608][768] @ Wt^T ; epilogue: +bq & *0.125 (Q), +bv (V)
__launch_bounds__(256, 2)
__global__ void kgemm(const bf* __restrict__ X, const bf* __restrict__ Wt,
                      const float* __restrict__ bq, const float* __restrict__ bv,
                      bf* __restrict__ C) {
    __shared__ __align__(16) bf smA[128 * 64];   // 16 KiB
    __shared__ __align__(16) bf smB[256 * 64];   // 32 KiB  (48 KiB total)
    const int tid  = threadIdx.x;
    const int wave = tid >> 6, lane = tid & 63;
    const int quad = lane >> 4, l16 = lane & 15;
    const int m0 = blockIdx.x * 128;     // gridDim.x = 99 (last tile partial)
    const int n0 = blockIdx.y * 256;     // gridDim.y = 9 (exact)
    const int wm  = (wave >> 1) * 64;    // 2 M groups
    const int wnl = (wave & 1) * 128;    // 2 N groups (128 cols each)
    const int swz = l16 & 7;             // read-side XOR (row & 7 == l16 & 7)

    v4f acc[4][8];
#pragma unroll
    for (int i = 0; i < 4; i++)
#pragma unroll
        for (int j = 0; j < 8; j++) acc[i][j] = (v4f){0.f, 0.f, 0.f, 0.f};

    for (int k0 = 0; k0 < HID; k0 += 64) {
        // stage A: 128 rows x 8 chunks = 1024 chunks (4 rounds of 256)
#pragma unroll
        for (int c = 0; c < 4; c++) {
            int chunkbase = c * 256 + wave * 64;       // wave-uniform
            int chunk = chunkbase + lane;
            int row = chunk >> 3;
            int cc  = (chunk & 7) ^ (row & 7);         // inverse-swizzled source col
            int arow = m0 + row; if (arow > MTOT - 1) arow = MTOT - 1;
            gload_lds16(X + (size_t)arow * HID + k0 + cc * 8, smA + chunkbase * 8);
        }
        // stage B: 256 rows x 8 chunks = 2048 chunks (8 rounds of 256)
#pragma unroll
        for (int c = 0; c < 8; c++) {
            int chunkbase = c * 256 + wave * 64;
            int chunk = chunkbase + lane;
            int row = chunk >> 3;
            int cc  = (chunk & 7) ^ (row & 7);
            gload_lds16(Wt + (size_t)(n0 + row) * HID + k0 + cc * 8, smB + chunkbase * 8);
        }
        __syncthreads();
#pragma unroll
        for (int ks = 0; ks < 2; ks++) {
            v8bf afr[4], bfr[8];
#pragma unroll
            for (int i = 0; i < 4; i++)
                afr[i] = *(const v8bf*)(smA + (wm + i * 16 + l16) * 64 + ((ks * 4 + quad) ^ swz) * 8);
#pragma unroll
            for (int j = 0; j < 8; j++)
                bfr[j] = *(const v8bf*)(smB + (wnl + j * 16 + l16) * 64 + ((ks * 4 + quad) ^ swz) * 8);
#pragma unroll
            for (int i = 0; i < 4; i++)
#pragma unroll
                for (int j = 0; j < 8; j++)
                    acc[i][j] = __builtin_amdgcn_mfma_f32_16x16x32_bf16(
                        afr[i], bfr[j], acc[i][j], 0, 0, 0);
        }
        __syncthreads();
    }

#pragma unroll
    for (int i = 0; i < 4; i++) {
        int mbase = m0 + wm + i * 16 + quad * 4;
#pragma unroll
        for (int j = 0; j < 8; j++) {
            int n = n0 + wnl + j * 16 + l16;
#pragma unroll
            for (int r = 0; r < 4; r++) {
                int m = mbase + r;
                if (m < MTOT) {
                    float v = acc[i][j][r];
                    if (n < 768)        v = (v + bq[n]) * 0.125f;   // Q: +bq, *1/sqrt(64)
                    else if (n >= 1536) v = v + bv[n - 1536];       // V: +bv
                    C[(size_t)m * NQKV + n] = (bf)v;
                }
            }
        }
    }
}

// ---------------- kernel 4: attention — round-10 form (unchanged) -----------
__launch_bounds__(512, 1)
__global__ void kattn(const bf* __restrict__ C, const float* __restrict__ bias,
                      float* __restrict__ out) {
    __shared__ __align__(16) bf sK[208 * 64];      // [kpos][d], XOR-swizzled cols
    __shared__ __align__(16) bf sV[64 * VP];       // transposed [d][kpos]
    __shared__ __align__(16) bf sP[8][16 * VP];    // per-wave P; head = V scratch
    bf* scratch = &sP[0][0];                       // [224][64] linear V staging
    const int tid  = threadIdx.x;
    const int wave = tid >> 6, lane = tid & 63;
    const int quad = lane >> 4, l16 = lane & 15;
    const int b = blockIdx.x / HEADS, h = blockIdx.x % HEADS;
    const bf* Cb = C + (size_t)b * SEQ * NQKV;
    const int swz = l16 & 7;

    // ---- stage K [208][64] swizzled: 1664 chunks of 16B ----
    for (int cb = wave * 64; cb < 1664; cb += 512) {
        int ch  = cb + lane;
        int row = ch >> 3, c = ch & 7;
        int cc  = c ^ (row & 7);
        int s   = row > 196 ? 196 : row;
        gload_lds16(Cb + (size_t)s * NQKV + 768 + h * 64 + cc * 8, sK + cb * 8);
    }
    // ---- stage V [224][64] linear into scratch: 1792 chunks ----
    for (int cb = wave * 64; cb < 1792; cb += 512) {
        int ch  = cb + lane;
        int row = ch >> 3, c = ch & 7;
        int s   = row > 196 ? 196 : row;
        gload_lds16(Cb + (size_t)s * NQKV + 1536 + h * 64 + c * 8, scratch + cb * 8);
    }
    __syncthreads();

    // ---- transpose scratch[224][64] -> sV[64][VP] ----
    {
        bf tv[8];
        int chunk = tid;
        for (; chunk < 1792; chunk += 512) {
            int d = chunk & 63, sc = chunk >> 6;
#pragma unroll
            for (int t = 0; t < 8; t++) tv[t] = scratch[(sc * 8 + t) * 64 + d];
            *(uint4*)(sV + d * VP + sc * 8) = *(uint4*)tv;
        }
    }
    __syncthreads();

    const float* biash = bias + (size_t)h * 208 * 208;

    for (int st = wave; st < 13; st += 8) {
        int s0 = st * 16;
        int qrow = s0 + l16; if (qrow > SEQ - 1) qrow = SEQ - 1;
        v8bf aQ[2];
#pragma unroll
        for (int ks = 0; ks < 2; ks++)
            aQ[ks] = *(const v8bf*)(Cb + (size_t)qrow * NQKV + h * 64 + ks * 32 + quad * 8);

        v4f sc[13];
#pragma unroll
        for (int nt = 0; nt < 13; nt++) {
            v4f a = (v4f){0.f, 0.f, 0.f, 0.f};
#pragma unroll
            for (int ks = 0; ks < 2; ks++) {
                v8bf bK = *(const v8bf*)(sK + (nt * 16 + l16) * 64 + ((ks * 4 + quad) ^ swz) * 8);
                a = __builtin_amdgcn_mfma_f32_16x16x32_bf16(aQ[ks], bK, a, 0, 0, 0);
            }
            sc[nt] = a;
        }
#pragma unroll
        for (int nt = 0; nt < 13; nt++) {
            int j = nt * 16 + l16;
#pragma unroll
            for (int r = 0; r < 4; r++) {
                int i = s0 + quad * 4 + r;
                float v = sc[nt][r] + biash[i * 208 + j];
                if (j >= SEQ) v = -1e30f;
                sc[nt][r] = v;
            }
        }
        float inv[4];
#pragma unroll
        for (int r = 0; r < 4; r++) {
            float m = sc[0][r];
#pragma unroll
            for (int nt = 1; nt < 13; nt++) m = fmaxf(m, sc[nt][r]);
#pragma unroll
            for (int off = 1; off < 16; off <<= 1) m = fmaxf(m, __shfl_xor(m, off, 16));
            float sum = 0.f;
#pragma unroll
            for (int nt = 0; nt < 13; nt++) {
                float e = __expf(sc[nt][r] - m);
                sc[nt][r] = e; sum += e;
            }
#pragma unroll
            for (int off = 1; off < 16; off <<= 1) sum += __shfl_xor(sum, off, 16);
            inv[r] = 1.f / sum;
        }
        bf* P = sP[wave];
#pragma unroll
        for (int nt = 0; nt < 13; nt++) {
            int j = nt * 16 + l16;
#pragma unroll
            for (int r = 0; r < 4; r++)
                P[(quad * 4 + r) * VP + j] = (bf)sc[nt][r];
        }
        *(uint2*)(P + l16 * VP + 208 + quad * 4) = make_uint2(0, 0);

        v4f o[4];
#pragma unroll
        for (int n2 = 0; n2 < 4; n2++) o[n2] = (v4f){0.f, 0.f, 0.f, 0.f};
#pragma unroll
        for (int ks = 0; ks < 7; ks++) {
            v8bf aP = *(const v8bf*)(P + l16 * VP + ks * 32 + quad * 8);
#pragma unroll
            for (int n2 = 0; n2 < 4; n2++) {
                v8bf bV = *(const v8bf*)(sV + (n2 * 16 + l16) * VP + ks * 32 + quad * 8);
                o[n2] = __builtin_amdgcn_mfma_f32_16x16x32_bf16(aP, bV, o[n2], 0, 0, 0);
            }
        }
#pragma unroll
        for (int r = 0; r < 4; r++) {
            int s = s0 + quad * 4 + r;
            if (s < SEQ) {
#pragma unroll
                for (int n2 = 0; n2 < 4; n2++) {
                    int d = n2 * 16 + l16;
                    out[((size_t)b * SEQ + s) * HID + h * 64 + d] = o[n2][r] * inv[r];
                }
            }
        }
    }
}

// ---------------- launcher (3 launches) -------------------------------------
extern "C" void kernel_launch(void* const* d_in, const int* in_sizes, int n_in,
                              void* d_out, int out_size, void* d_ws, size_t ws_size,
                              hipStream_t stream) {
    const float* X   = (const float*)d_in[0];
    const float* wq  = (const float*)d_in[1];
    const float* bq  = (const float*)d_in[2];
    const float* wk  = (const float*)d_in[3];
    const float* wv  = (const float*)d_in[4];
    const float* bv  = (const float*)d_in[5];
    const float* tbl = (const float*)d_in[6];
    float* out = (float*)d_out;

    char* ws = (char*)d_ws;
    bf*    Xb   = (bf*)ws;                          // 12608*768*2  = 19,365,888 B
    bf*    Wt   = (bf*)(ws + 19365888);             // 2304*768*2   =  3,538,944 B
    bf*    C    = (bf*)(ws + 22904832);             // 12608*2304*2 = 58,097,664 B
    float* bias = (float*)(ws + 81002496);          // 12*208*208*4 =  2,076,672 B

    kprep<<<11916, 256, 0, stream>>>(X, Xb, wq, wk, wv, Wt, tbl, bias);
    dim3 g(99, 9);
    kgemm<<<g, 256, 0, stream>>>(Xb, Wt, bq, bv, C);
    kattn<<<768, 512, 0, stream>>>(C, bias, out);
}

// Round 12
// 202.261 us; speedup vs baseline: 1.1089x; 1.1089x over previous
//
#include <hip/hip_runtime.h>
#include <hip/hip_bf16.h>
#include <stdint.h>

typedef __bf16 bf;
typedef __bf16 v8bf __attribute__((ext_vector_type(8)));
typedef float v4f __attribute__((ext_vector_type(4)));

#define SEQ   197
#define HEADS 12
#define HID   768
#define NQKV  2304
#define MTOT  12608   // 64*197
#define VP    232     // sV/sP pitch (elems): 464 B mod 128 = 80 -> 16B-slot spread

__device__ __forceinline__ void gload_lds16(const void* g, void* l) {
    __builtin_amdgcn_global_load_lds(
        (const __attribute__((address_space(1))) void*)g,
        (__attribute__((address_space(3))) void*)l, 16, 0, 0);
}

// ---------------- kernel 0: fused prep (kx + kwt + kbias in one launch) -----
__global__ void kprep(const float* __restrict__ x, bf* __restrict__ xb,
                      const float* __restrict__ wq, const float* __restrict__ wk,
                      const float* __restrict__ wv, bf* __restrict__ wt,
                      const float* __restrict__ table, float* __restrict__ bias) {
    __shared__ float t[64][65];
    const int bid = blockIdx.x;

    if (bid < 9456) {
        int idx = bid * 256 + threadIdx.x;
        float4 v = ((const float4*)x)[idx];
        bf o[4] = {(bf)v.x, (bf)v.y, (bf)v.z, (bf)v.w};
        ((uint2*)xb)[idx] = *(uint2*)o;
        return;
    }

    if (bid < 9456 + 432) {
        int bz = bid - 9456;
        int z  = bz / 144;
        int rr = bz % 144;
        int bx = rr % 12;
        int by = rr / 12;
        const float* W = (z == 0) ? wq : (z == 1 ? wk : wv);
        int kt = bx * 64, nt = by * 64;
        int r  = threadIdx.x >> 4;
        int c4 = (threadIdx.x & 15) * 4;
#pragma unroll
        for (int p = 0; p < 64; p += 16) {
            float4 v = *(const float4*)(W + (size_t)(kt + p + r) * 768 + nt + c4);
            t[p + r][c4 + 0] = v.x; t[p + r][c4 + 1] = v.y;
            t[p + r][c4 + 2] = v.z; t[p + r][c4 + 3] = v.w;
        }
        __syncthreads();
#pragma unroll
        for (int p = 0; p < 64; p += 16) {
            int i = p + r;
            bf o[4];
#pragma unroll
            for (int j = 0; j < 4; j++) o[j] = (bf)t[c4 + j][i];
            *(uint2*)(wt + (size_t)(z * 768 + nt + i) * 768 + kt + c4) = *(uint2*)o;
        }
        return;
    }

    int idx = (bid - 9888) * 256 + threadIdx.x;
    int h = idx / (208 * 208);
    int r = idx % (208 * 208);
    int i = r / 208, j = r % 208;
    float v = 0.f;
    if (i < SEQ && j < SEQ) {
        int rpi;
        if (i == 0 && j == 0)      rpi = 731;
        else if (i == 0)           rpi = 729;
        else if (j == 0)           rpi = 730;
        else {
            int hp = (i - 1) / 14, wp = (i - 1) % 14;
            int hq = (j - 1) / 14, wq = (j - 1) % 14;
            rpi = (hp - hq + 13) * 27 + (wp - wq + 13);
        }
        v = table[rpi * 12 + h];
    }
    bias[idx] = v;
}

// ---------------- kernel 3: fused QKV GEMM — EXACT round-6 kernel + T1 ------
// (round-6 form = measured family optimum: 84.2 us, 0 conflicts; tile/BK/
// pipeline/occupancy sweeps all closed). ONE change: XCD-chunked bijective
// blockIdx swizzle (m204 formula; nwg = 1782 = 8*222+6) with y-fastest work
// id, so the 18 blocks sharing an X row-tile are CONSECUTIVE work ids ->
// same XCD -> X tile fetched ~once per XCD instead of ~8x.
// C[12608][2304] = Xb[12608][768] @ Wt^T ; epilogue: +bq & *0.125 (Q), +bv (V)
__launch_bounds__(256, 2)
__global__ void kgemm(const bf* __restrict__ X, const bf* __restrict__ Wt,
                      const float* __restrict__ bq, const float* __restrict__ bv,
                      bf* __restrict__ C) {
    __shared__ __align__(16) bf smA[128 * 64];
    __shared__ __align__(16) bf smB[128 * 64];
    const int tid  = threadIdx.x;
    const int wave = tid >> 6, lane = tid & 63;
    const int quad = lane >> 4, l16 = lane & 15;
    // T1: dispatch id -> XCD-chunked work id (bijective; 1782 = 6*223 + 2*222)
    const int di  = blockIdx.x + blockIdx.y * 99;
    const int xcd = di & 7, ix = di >> 3;
    const int w   = (xcd < 6) ? xcd * 223 + ix : 1338 + (xcd - 6) * 222 + ix;
    const int m0 = (w / 18) * 128;       // consecutive w share the X row-tile
    const int n0 = (w % 18) * 128;
    const int wm = (wave >> 1) * 64, wn = (wave & 1) * 64;
    const int swz = l16 & 7;             // read-side XOR (row & 7 == l16 & 7)

    v4f acc[4][4];
#pragma unroll
    for (int i = 0; i < 4; i++)
#pragma unroll
        for (int j = 0; j < 4; j++) acc[i][j] = (v4f){0.f, 0.f, 0.f, 0.f};

    for (int k0 = 0; k0 < HID; k0 += 64) {
#pragma unroll
        for (int c = 0; c < 4; c++) {
            int chunkbase = c * 256 + wave * 64;       // wave-uniform
            int chunk = chunkbase + lane;
            int row = chunk >> 3;
            int cc  = (chunk & 7) ^ (row & 7);         // inverse-swizzled source col
            int arow = m0 + row; if (arow > MTOT - 1) arow = MTOT - 1;
            gload_lds16(X  + (size_t)arow * HID + k0 + cc * 8, smA + chunkbase * 8);
            gload_lds16(Wt + (size_t)(n0 + row) * HID + k0 + cc * 8, smB + chunkbase * 8);
        }
        __syncthreads();
#pragma unroll
        for (int ks = 0; ks < 2; ks++) {
            v8bf afr[4], bfr[4];
#pragma unroll
            for (int i = 0; i < 4; i++)
                afr[i] = *(const v8bf*)(smA + (wm + i * 16 + l16) * 64 + ((ks * 4 + quad) ^ swz) * 8);
#pragma unroll
            for (int j = 0; j < 4; j++)
                bfr[j] = *(const v8bf*)(smB + (wn + j * 16 + l16) * 64 + ((ks * 4 + quad) ^ swz) * 8);
#pragma unroll
            for (int i = 0; i < 4; i++)
#pragma unroll
                for (int j = 0; j < 4; j++)
                    acc[i][j] = __builtin_amdgcn_mfma_f32_16x16x32_bf16(
                        afr[i], bfr[j], acc[i][j], 0, 0, 0);
        }
        __syncthreads();
    }

#pragma unroll
    for (int i = 0; i < 4; i++) {
        int mbase = m0 + wm + i * 16 + quad * 4;
#pragma unroll
        for (int j = 0; j < 4; j++) {
            int n = n0 + wn + j * 16 + l16;
#pragma unroll
            for (int r = 0; r < 4; r++) {
                int m = mbase + r;
                if (m < MTOT) {
                    float v = acc[i][j][r];
                    if (n < 768)        v = (v + bq[n]) * 0.125f;   // Q: +bq, *1/sqrt(64)
                    else if (n >= 1536) v = v + bv[n - 1536];       // V: +bv
                    C[(size_t)m * NQKV + n] = (bf)v;
                }
            }
        }
    }
}

// ---------------- kernel 4: attention — round-10 form + T1 swizzle ----------
// 768 blocks = 8*96 exact: w = (i&7)*96 + (i>>3). Consecutive w share the
// batch b -> one XCD sees all 12 heads of a batch -> C panel (0.9 MB/b)
// fetched once per XCD instead of up to 8x.
__launch_bounds__(512, 1)
__global__ void kattn(const bf* __restrict__ C, const float* __restrict__ bias,
                      float* __restrict__ out) {
    __shared__ __align__(16) bf sK[208 * 64];      // [kpos][d], XOR-swizzled cols
    __shared__ __align__(16) bf sV[64 * VP];       // transposed [d][kpos]
    __shared__ __align__(16) bf sP[8][16 * VP];    // per-wave P; head = V scratch
    bf* scratch = &sP[0][0];                       // [224][64] linear V staging
    const int tid  = threadIdx.x;
    const int wave = tid >> 6, lane = tid & 63;
    const int quad = lane >> 4, l16 = lane & 15;
    const int wk_ = (blockIdx.x & 7) * 96 + (blockIdx.x >> 3);   // T1 remap
    const int b = wk_ / HEADS, h = wk_ % HEADS;
    const bf* Cb = C + (size_t)b * SEQ * NQKV;
    const int swz = l16 & 7;

    // ---- stage K [208][64] swizzled: 1664 chunks of 16B ----
    for (int cb = wave * 64; cb < 1664; cb += 512) {
        int ch  = cb + lane;
        int row = ch >> 3, c = ch & 7;
        int cc  = c ^ (row & 7);
        int s   = row > 196 ? 196 : row;
        gload_lds16(Cb + (size_t)s * NQKV + 768 + h * 64 + cc * 8, sK + cb * 8);
    }
    // ---- stage V [224][64] linear into scratch: 1792 chunks ----
    for (int cb = wave * 64; cb < 1792; cb += 512) {
        int ch  = cb + lane;
        int row = ch >> 3, c = ch & 7;
        int s   = row > 196 ? 196 : row;
        gload_lds16(Cb + (size_t)s * NQKV + 1536 + h * 64 + c * 8, scratch + cb * 8);
    }
    __syncthreads();

    // ---- transpose scratch[224][64] -> sV[64][VP] ----
    {
        bf tv[8];
        int chunk = tid;
        for (; chunk < 1792; chunk += 512) {
            int d = chunk & 63, sc = chunk >> 6;
#pragma unroll
            for (int t = 0; t < 8; t++) tv[t] = scratch[(sc * 8 + t) * 64 + d];
            *(uint4*)(sV + d * VP + sc * 8) = *(uint4*)tv;
        }
    }
    __syncthreads();

    const float* biash = bias + (size_t)h * 208 * 208;

    for (int st = wave; st < 13; st += 8) {
        int s0 = st * 16;
        int qrow = s0 + l16; if (qrow > SEQ - 1) qrow = SEQ - 1;
        v8bf aQ[2];
#pragma unroll
        for (int ks = 0; ks < 2; ks++)
            aQ[ks] = *(const v8bf*)(Cb + (size_t)qrow * NQKV + h * 64 + ks * 32 + quad * 8);

        v4f sc[13];
#pragma unroll
        for (int nt = 0; nt < 13; nt++) {
            v4f a = (v4f){0.f, 0.f, 0.f, 0.f};
#pragma unroll
            for (int ks = 0; ks < 2; ks++) {
                v8bf bK = *(const v8bf*)(sK + (nt * 16 + l16) * 64 + ((ks * 4 + quad) ^ swz) * 8);
                a = __builtin_amdgcn_mfma_f32_16x16x32_bf16(aQ[ks], bK, a, 0, 0, 0);
            }
            sc[nt] = a;
        }
#pragma unroll
        for (int nt = 0; nt < 13; nt++) {
            int j = nt * 16 + l16;
#pragma unroll
            for (int r = 0; r < 4; r++) {
                int i = s0 + quad * 4 + r;
                float v = sc[nt][r] + biash[i * 208 + j];
                if (j >= SEQ) v = -1e30f;
                sc[nt][r] = v;
            }
        }
        float inv[4];
#pragma unroll
        for (int r = 0; r < 4; r++) {
            float m = sc[0][r];
#pragma unroll
            for (int nt = 1; nt < 13; nt++) m = fmaxf(m, sc[nt][r]);
#pragma unroll
            for (int off = 1; off < 16; off <<= 1) m = fmaxf(m, __shfl_xor(m, off, 16));
            float sum = 0.f;
#pragma unroll
            for (int nt = 0; nt < 13; nt++) {
                float e = __expf(sc[nt][r] - m);
                sc[nt][r] = e; sum += e;
            }
#pragma unroll
            for (int off = 1; off < 16; off <<= 1) sum += __shfl_xor(sum, off, 16);
            inv[r] = 1.f / sum;
        }
        bf* P = sP[wave];
#pragma unroll
        for (int nt = 0; nt < 13; nt++) {
            int j = nt * 16 + l16;
#pragma unroll
            for (int r = 0; r < 4; r++)
                P[(quad * 4 + r) * VP + j] = (bf)sc[nt][r];
        }
        *(uint2*)(P + l16 * VP + 208 + quad * 4) = make_uint2(0, 0);

        v4f o[4];
#pragma unroll
        for (int n2 = 0; n2 < 4; n2++) o[n2] = (v4f){0.f, 0.f, 0.f, 0.f};
#pragma unroll
        for (int ks = 0; ks < 7; ks++) {
            v8bf aP = *(const v8bf*)(P + l16 * VP + ks * 32 + quad * 8);
#pragma unroll
            for (int n2 = 0; n2 < 4; n2++) {
                v8bf bV = *(const v8bf*)(sV + (n2 * 16 + l16) * VP + ks * 32 + quad * 8);
                o[n2] = __builtin_amdgcn_mfma_f32_16x16x32_bf16(aP, bV, o[n2], 0, 0, 0);
            }
        }
#pragma unroll
        for (int r = 0; r < 4; r++) {
            int s = s0 + quad * 4 + r;
            if (s < SEQ) {
#pragma unroll
                for (int n2 = 0; n2 < 4; n2++) {
                    int d = n2 * 16 + l16;
                    out[((size_t)b * SEQ + s) * HID + h * 64 + d] = o[n2][r] * inv[r];
                }
            }
        }
    }
}

// ---------------- launcher (3 launches) -------------------------------------
extern "C" void kernel_launch(void* const* d_in, const int* in_sizes, int n_in,
                              void* d_out, int out_size, void* d_ws, size_t ws_size,
                              hipStream_t stream) {
    const float* X   = (const float*)d_in[0];
    const float* wq  = (const float*)d_in[1];
    const float* bq  = (const float*)d_in[2];
    const float* wk  = (const float*)d_in[3];
    const float* wv  = (const float*)d_in[4];
    const float* bv  = (const float*)d_in[5];
    const float* tbl = (const float*)d_in[6];
    float* out = (float*)d_out;

    char* ws = (char*)d_ws;
    bf*    Xb   = (bf*)ws;                          // 12608*768*2  = 19,365,888 B
    bf*    Wt   = (bf*)(ws + 19365888);             // 2304*768*2   =  3,538,944 B
    bf*    C    = (bf*)(ws + 22904832);             // 12608*2304*2 = 58,097,664 B
    float* bias = (float*)(ws + 81002496);          // 12*208*208*4 =  2,076,672 B

    kprep<<<11916, 256, 0, stream>>>(X, Xb, wq, wk, wv, Wt, tbl, bias);
    dim3 g(99, 18);
    kgemm<<<g, 256, 0, stream>>>(Xb, Wt, bq, bv, C);
    kattn<<<768, 512, 0, stream>>>(C, bias, out);
}